// Round 1
// baseline (37978.351 us; speedup 1.0000x reference)
//
#include <hip/hip_runtime.h>
#include <math.h>

// NTM recurrence, fp32 baseline.
// B=256 T=128 I=512 H=512 N=1024 M=512 O=512
#define B_ 256
#define T_ 128
#define I_ 512
#define H_ 512
#define N_ 1024
#define M_ 512
#define O_ 512
#define EPS_ 1e-8f

// ---------------- small math helpers ----------------
__device__ __forceinline__ float sigm_(float x) { return 1.f / (1.f + expf(-x)); }
__device__ __forceinline__ float softplus_(float x) { return x > 20.f ? x : log1pf(expf(x)); }

__device__ __forceinline__ float wave_sum_(float v) {
#pragma unroll
    for (int o = 32; o > 0; o >>= 1) v += __shfl_down(v, o);
    return v;
}
__device__ __forceinline__ float wave_max_(float v) {
#pragma unroll
    for (int o = 32; o > 0; o >>= 1) v = fmaxf(v, __shfl_down(v, o));
    return v;
}
// blockDim.x multiple of 64; s needs >= 8 floats
__device__ float block_sum_(float v, float* s) {
    int lane = threadIdx.x & 63, wid = threadIdx.x >> 6, nw = blockDim.x >> 6;
    v = wave_sum_(v);
    if (lane == 0) s[wid] = v;
    __syncthreads();
    float r = (threadIdx.x < nw) ? s[threadIdx.x] : 0.f;
    if (wid == 0) { r = wave_sum_(r); if (lane == 0) s[0] = r; }
    __syncthreads();
    float out = s[0];
    __syncthreads();
    return out;
}
__device__ float block_max_(float v, float* s) {
    int lane = threadIdx.x & 63, wid = threadIdx.x >> 6, nw = blockDim.x >> 6;
    v = wave_max_(v);
    if (lane == 0) s[wid] = v;
    __syncthreads();
    float r = (threadIdx.x < nw) ? s[threadIdx.x] : -3.4e38f;
    if (wid == 0) { r = wave_max_(r); if (lane == 0) s[0] = r; }
    __syncthreads();
    float out = s[0];
    __syncthreads();
    return out;
}

// ---------------- epilogue functors ----------------
struct EpiEA {  // ea = h@Wea + bea -> e=sigmoid(:M), a=tanh(M:)
    const float* bea; float* e; float* a;
    __device__ void operator()(int r, int c, float v) const {
        v += bea[c];
        if (c < M_) e[r * M_ + c] = sigm_(v);
        else        a[r * M_ + (c - M_)] = tanhf(v);
    }
};
struct EpiStoreR {  // r = wr@mem
    float* C;
    __device__ void operator()(int r, int c, float v) const { C[r * M_ + c] = v; }
};
struct EpiH {  // h = tanh(xwx_t + r@Wr + bh)
    const float* xwxt; const float* bh; float* h;
    __device__ void operator()(int r, int c, float v) const {
        h[r * H_ + c] = tanhf(v + xwxt[r * H_ + c] + bh[c]);
    }
};
struct EpiP {  // p = h@Wh + b  (raw, per-head base already offset)
    const float* bias; float* p;
    __device__ void operator()(int r, int c, float v) const {
        p[r * (M_ + 6) + c] = v + bias[c];
    }
};
struct EpiOut {  // out[b,t,:] = sigmoid(h@Wo + bo); outt = d_out + t*O
    const float* bo; float* outt;
    __device__ void operator()(int r, int c, float v) const {
        outt[r * (T_ * O_) + c] = sigm_(v + bo[c]);
    }
};

// ---------------- generic NN GEMM: C[r,c] = sum_k A[r,k]*B[k,c], epilogue ----------------
// 256 threads, tile TM x TN, TK=16. tm=TM/16, tn=TN/16 per-thread tile.
template <int TM, int TN, class Epi>
__global__ __launch_bounds__(256) void gemm_nn(const float* __restrict__ A, int lda,
                                               const float* __restrict__ B, int ldb,
                                               int K, int Ncols, Epi epi) {
    constexpr int TK = 16;
    constexpr int tm = TM / 16, tn = TN / 16;
    __shared__ __align__(16) float As[TK][TM + 4];
    __shared__ __align__(16) float Bs[TK][TN + 4];
    int tid = threadIdx.x;
    int row0 = blockIdx.y * TM, col0 = blockIdx.x * TN;
    int tx = tid & 15, ty = tid >> 4;
    // A load: tm contiguous k per thread
    int ar = tid / (16 / tm);
    int ak = (tid % (16 / tm)) * tm;
    // B load: tn contiguous cols per thread
    int bk = tid >> 4;
    int bn = (tid & 15) * tn;
    float acc[tm][tn];
#pragma unroll
    for (int i = 0; i < tm; i++)
#pragma unroll
        for (int j = 0; j < tn; j++) acc[i][j] = 0.f;

    for (int k0 = 0; k0 < K; k0 += TK) {
#pragma unroll
        for (int j = 0; j < tm; j++)
            As[ak + j][ar] = A[(row0 + ar) * lda + k0 + ak + j];
#pragma unroll
        for (int j = 0; j < tn; j++) {
            int c = col0 + bn + j;
            Bs[bk][bn + j] = (c < Ncols) ? B[(size_t)(k0 + bk) * ldb + c] : 0.f;
        }
        __syncthreads();
#pragma unroll
        for (int kk = 0; kk < TK; kk++) {
            float av[tm], bv[tn];
#pragma unroll
            for (int i = 0; i < tm; i++) av[i] = As[kk][ty * tm + i];
#pragma unroll
            for (int j = 0; j < tn; j++) bv[j] = Bs[kk][tx * tn + j];
#pragma unroll
            for (int i = 0; i < tm; i++)
#pragma unroll
                for (int j = 0; j < tn; j++) acc[i][j] += av[i] * bv[j];
        }
        __syncthreads();
    }
#pragma unroll
    for (int i = 0; i < tm; i++)
#pragma unroll
        for (int j = 0; j < tn; j++) {
            int r = row0 + ty * tm + i, c = col0 + tx * tn + j;
            if (c < Ncols) epi(r, c, acc[i][j]);
        }
}

// ---------------- xwx precompute: rows = t*B+b over all (t,b), C=x_t@Wx ----------------
__global__ __launch_bounds__(256) void gemm_xwx(const float* __restrict__ x,
                                                const float* __restrict__ Wx,
                                                float* __restrict__ xwx) {
    constexpr int TK = 16;
    __shared__ __align__(16) float As[TK][68];
    __shared__ __align__(16) float Bs[TK][68];
    int tid = threadIdx.x;
    int row0 = blockIdx.y * 64, col0 = blockIdx.x * 64;
    int tx = tid & 15, ty = tid >> 4;
    int ar = tid >> 2, ak = (tid & 3) * 4;
    int bk = tid >> 4, bn = (tid & 15) * 4;
    float acc[4][4];
#pragma unroll
    for (int i = 0; i < 4; i++)
#pragma unroll
        for (int j = 0; j < 4; j++) acc[i][j] = 0.f;

    int row = row0 + ar;
    const float* Arow = x + ((size_t)(row & (B_ - 1)) * T_ + (row >> 8)) * I_;
    for (int k0 = 0; k0 < I_; k0 += TK) {
#pragma unroll
        for (int j = 0; j < 4; j++) As[ak + j][ar] = Arow[k0 + ak + j];
#pragma unroll
        for (int j = 0; j < 4; j++) Bs[bk][bn + j] = Wx[(size_t)(k0 + bk) * H_ + col0 + bn + j];
        __syncthreads();
#pragma unroll
        for (int kk = 0; kk < TK; kk++) {
            float av[4], bv[4];
#pragma unroll
            for (int i = 0; i < 4; i++) av[i] = As[kk][ty * 4 + i];
#pragma unroll
            for (int j = 0; j < 4; j++) bv[j] = Bs[kk][tx * 4 + j];
#pragma unroll
            for (int i = 0; i < 4; i++)
#pragma unroll
                for (int j = 0; j < 4; j++) acc[i][j] += av[i] * bv[j];
        }
        __syncthreads();
    }
#pragma unroll
    for (int i = 0; i < 4; i++)
#pragma unroll
        for (int j = 0; j < 4; j++)
            xwx[(size_t)(row0 + ty * 4 + i) * H_ + col0 + tx * 4 + j] = acc[i][j];
}

// ---------------- mem update: Se=ww^T e, Sa=ww^T a; mem = mem*(1-Se/B)+Sa/B ----------------
__global__ __launch_bounds__(256) void memupd_kernel(const float* __restrict__ ww,
                                                     const float* __restrict__ e,
                                                     const float* __restrict__ a,
                                                     float* __restrict__ mem) {
    constexpr int TK = 16;
    __shared__ __align__(16) float Ws[TK][68];
    __shared__ __align__(16) float Es[TK][68];
    __shared__ __align__(16) float Aa[TK][68];
    int tid = threadIdx.x;
    int n0 = blockIdx.y * 64, m0 = blockIdx.x * 64;
    int tx = tid & 15, ty = tid >> 4;
    int bk = tid >> 4, bn = (tid & 15) * 4;
    float se[4][4], sa[4][4];
#pragma unroll
    for (int i = 0; i < 4; i++)
#pragma unroll
        for (int j = 0; j < 4; j++) { se[i][j] = 0.f; sa[i][j] = 0.f; }

    for (int k0 = 0; k0 < B_; k0 += TK) {
#pragma unroll
        for (int j = 0; j < 4; j++) {
            Ws[bk][bn + j] = ww[(size_t)(k0 + bk) * N_ + n0 + bn + j];
            Es[bk][bn + j] = e[(size_t)(k0 + bk) * M_ + m0 + bn + j];
            Aa[bk][bn + j] = a[(size_t)(k0 + bk) * M_ + m0 + bn + j];
        }
        __syncthreads();
#pragma unroll
        for (int kk = 0; kk < TK; kk++) {
            float wv[4], ev[4], av[4];
#pragma unroll
            for (int i = 0; i < 4; i++) wv[i] = Ws[kk][ty * 4 + i];
#pragma unroll
            for (int j = 0; j < 4; j++) { ev[j] = Es[kk][tx * 4 + j]; av[j] = Aa[kk][tx * 4 + j]; }
#pragma unroll
            for (int i = 0; i < 4; i++)
#pragma unroll
                for (int j = 0; j < 4; j++) { se[i][j] += wv[i] * ev[j]; sa[i][j] += wv[i] * av[j]; }
        }
        __syncthreads();
    }
    const float invB = 1.f / (float)B_;
#pragma unroll
    for (int i = 0; i < 4; i++)
#pragma unroll
        for (int j = 0; j < 4; j++) {
            size_t idx = (size_t)(n0 + ty * 4 + i) * M_ + m0 + tx * 4 + j;
            float old = mem[idx];
            mem[idx] = old * (1.f - se[i][j] * invB) + sa[i][j] * invB;
        }
}

// ---------------- scores NT GEMM: S[row,n] = kh[row,:] . mem[n,:] ----------------
__global__ __launch_bounds__(256) void gemm_scores(const float* __restrict__ kh,
                                                   const float* __restrict__ mem,
                                                   float* __restrict__ scores) {
    constexpr int TK = 16;
    __shared__ __align__(16) float As[TK][68];
    __shared__ __align__(16) float Bs[TK][68];
    int tid = threadIdx.x;
    int row0 = blockIdx.y * 64, n0 = blockIdx.x * 64;
    int tx = tid & 15, ty = tid >> 4;
    int ar = tid >> 2, ak = (tid & 3) * 4;
    float acc[4][4];
#pragma unroll
    for (int i = 0; i < 4; i++)
#pragma unroll
        for (int j = 0; j < 4; j++) acc[i][j] = 0.f;

    for (int k0 = 0; k0 < M_; k0 += TK) {
#pragma unroll
        for (int j = 0; j < 4; j++) {
            As[ak + j][ar] = kh[(size_t)(row0 + ar) * M_ + k0 + ak + j];
            Bs[ak + j][ar] = mem[(size_t)(n0 + ar) * M_ + k0 + ak + j];
        }
        __syncthreads();
#pragma unroll
        for (int kk = 0; kk < TK; kk++) {
            float av[4], bv[4];
#pragma unroll
            for (int i = 0; i < 4; i++) av[i] = As[kk][ty * 4 + i];
#pragma unroll
            for (int j = 0; j < 4; j++) bv[j] = Bs[kk][tx * 4 + j];
#pragma unroll
            for (int i = 0; i < 4; i++)
#pragma unroll
                for (int j = 0; j < 4; j++) acc[i][j] += av[i] * bv[j];
        }
        __syncthreads();
    }
#pragma unroll
    for (int i = 0; i < 4; i++)
#pragma unroll
        for (int j = 0; j < 4; j++)
            scores[(size_t)(row0 + ty * 4 + i) * N_ + n0 + tx * 4 + j] = acc[i][j];
}

// ---------------- mem row inverse norms ----------------
__global__ __launch_bounds__(128) void rownorm_kernel(const float* __restrict__ mem,
                                                      float* __restrict__ invn) {
    __shared__ float red[8];
    int n = blockIdx.x;
    float s = 0.f;
    for (int i = threadIdx.x; i < M_; i += 128) { float v = mem[(size_t)n * M_ + i]; s += v * v; }
    s = block_sum_(s, red);
    if (threadIdx.x == 0) invn[n] = 1.f / (sqrtf(s) + EPS_);
}

// ---------------- head scalars: k=tanh(p[:M]) -> kh; rowscale=beta/(||k||+eps); g,s,gamma ----------------
__global__ __launch_bounds__(128) void headscal_kernel(const float* __restrict__ p,
                                                       float* __restrict__ kh,
                                                       float* __restrict__ rowscale,
                                                       float* __restrict__ params) {
    __shared__ float red[8];
    int row = blockIdx.x;
    const float* pr = p + (size_t)row * (M_ + 6);
    float s = 0.f;
    for (int i = threadIdx.x; i < M_; i += 128) {
        float t = tanhf(pr[i]);
        kh[(size_t)row * M_ + i] = t;
        s += t * t;
    }
    s = block_sum_(s, red);
    if (threadIdx.x == 0) {
        float beta = softplus_(pr[M_]);
        rowscale[row] = beta / (sqrtf(s) + EPS_);
        float g = sigm_(pr[M_ + 1]);
        float a0 = pr[M_ + 2], a1 = pr[M_ + 3], a2 = pr[M_ + 4];
        float mx = fmaxf(a0, fmaxf(a1, a2));
        float e0 = expf(a0 - mx), e1 = expf(a1 - mx), e2 = expf(a2 - mx);
        float es = e0 + e1 + e2;
        float gamma = 1.f + softplus_(pr[M_ + 5]);
        params[row * 8 + 0] = g;
        params[row * 8 + 1] = e0 / es;
        params[row * 8 + 2] = e1 / es;
        params[row * 8 + 3] = e2 / es;
        params[row * 8 + 4] = gamma;
    }
}

// ---------------- addressing tail: softmax -> interpolate -> shift -> sharpen -> normalize ----------------
// rows 0..255 = write head (ww), 256..511 = read head (wr). In-place w update.
__global__ __launch_bounds__(256) void addr_kernel(const float* __restrict__ scores,
                                                   const float* __restrict__ invn,
                                                   const float* __restrict__ rowscale,
                                                   const float* __restrict__ params,
                                                   float* __restrict__ ww,
                                                   float* __restrict__ wr) {
    __shared__ float wgs[N_];
    __shared__ float red[8];
    int row = blockIdx.x;
    int head = row >> 8;
    int b = row & (B_ - 1);
    float* w = (head == 0) ? ww : wr;
    const float* sc = scores + (size_t)row * N_;
    const float* pr = params + row * 8;
    float g = pr[0], s0 = pr[1], s1 = pr[2], s2 = pr[3], gamma = pr[4];
    float rs = rowscale[row];
    int tid = threadIdx.x;

    float l[4];
#pragma unroll
    for (int j = 0; j < 4; j++) {
        int n = tid * 4 + j;
        l[j] = rs * invn[n] * sc[n];
    }
    float mx = fmaxf(fmaxf(l[0], l[1]), fmaxf(l[2], l[3]));
    mx = block_max_(mx, red);
    float ex[4]; float sum = 0.f;
#pragma unroll
    for (int j = 0; j < 4; j++) { ex[j] = expf(l[j] - mx); sum += ex[j]; }
    sum = block_sum_(sum, red);
    float inv = 1.f / sum;

    float wprev[4];
#pragma unroll
    for (int j = 0; j < 4; j++) wprev[j] = w[(size_t)b * N_ + tid * 4 + j];
#pragma unroll
    for (int j = 0; j < 4; j++) wgs[tid * 4 + j] = g * ex[j] * inv + (1.f - g) * wprev[j];
    __syncthreads();

    float wp[4]; float psum = 0.f;
#pragma unroll
    for (int j = 0; j < 4; j++) {
        int n = tid * 4 + j;
        float wt = s0 * wgs[(n + 1) & (N_ - 1)] + s1 * wgs[n] + s2 * wgs[(n - 1) & (N_ - 1)];
        float v = expf(gamma * logf(wt));
        wp[j] = v; psum += v;
    }
    psum = block_sum_(psum, red);
    float invp = 1.f / (psum + EPS_);
#pragma unroll
    for (int j = 0; j < 4; j++) w[(size_t)b * N_ + tid * 4 + j] = wp[j] * invp;
}

// ---------------- host ----------------
extern "C" void kernel_launch(void* const* d_in, const int* in_sizes, int n_in,
                              void* d_out, int out_size, void* d_ws, size_t ws_size,
                              hipStream_t stream) {
    const float* x    = (const float*)d_in[0];
    const float* mem0 = (const float*)d_in[1];
    const float* wr0  = (const float*)d_in[2];
    const float* ww0  = (const float*)d_in[3];
    const float* h0   = (const float*)d_in[4];
    const float* Wx   = (const float*)d_in[5];
    const float* Wr   = (const float*)d_in[6];
    const float* bh   = (const float*)d_in[7];
    const float* Whr  = (const float*)d_in[8];
    const float* bhr  = (const float*)d_in[9];
    const float* Whw  = (const float*)d_in[10];
    const float* bhw  = (const float*)d_in[11];
    const float* Wea  = (const float*)d_in[12];
    const float* bea  = (const float*)d_in[13];
    const float* Wo   = (const float*)d_in[14];
    const float* bo   = (const float*)d_in[15];
    float* out = (float*)d_out;

    float* ws = (float*)d_ws;
    size_t o = 0;
    float* xwx   = ws + o; o += (size_t)T_ * B_ * H_;   // 16.7M
    float* mem   = ws + o; o += (size_t)N_ * M_;
    float* wr    = ws + o; o += (size_t)B_ * N_;
    float* ww    = ws + o; o += (size_t)B_ * N_;
    float* h     = ws + o; o += (size_t)B_ * H_;
    float* e     = ws + o; o += (size_t)B_ * M_;
    float* a     = ws + o; o += (size_t)B_ * M_;
    float* r     = ws + o; o += (size_t)B_ * M_;
    float* p     = ws + o; o += (size_t)2 * B_ * (M_ + 6);
    float* kh    = ws + o; o += (size_t)2 * B_ * M_;
    float* scores= ws + o; o += (size_t)2 * B_ * N_;
    float* rowsc = ws + o; o += 512;
    float* params= ws + o; o += 512 * 8;
    float* invn  = ws + o; o += N_;

    // init state from inputs (ws is re-poisoned before every call)
    hipMemcpyAsync(mem, mem0, (size_t)N_ * M_ * 4, hipMemcpyDeviceToDevice, stream);
    hipMemcpyAsync(wr,  wr0,  (size_t)B_ * N_ * 4, hipMemcpyDeviceToDevice, stream);
    hipMemcpyAsync(ww,  ww0,  (size_t)B_ * N_ * 4, hipMemcpyDeviceToDevice, stream);
    hipMemcpyAsync(h,   h0,   (size_t)B_ * H_ * 4, hipMemcpyDeviceToDevice, stream);

    // precompute x_t @ Wx for all (t,b): rows t*B+b
    gemm_xwx<<<dim3(H_ / 64, (T_ * B_) / 64), 256, 0, stream>>>(x, Wx, xwx);

    for (int t = 0; t < T_; t++) {
        // 1. ea = h @ Wea + bea -> e, a
        gemm_nn<32, 64, EpiEA><<<dim3(2 * M_ / 64, B_ / 32), 256, 0, stream>>>(
            h, H_, Wea, 2 * M_, H_, 2 * M_, EpiEA{bea, e, a});
        // 2. mem update
        memupd_kernel<<<dim3(M_ / 64, N_ / 64), 256, 0, stream>>>(ww, e, a, mem);
        // 3. mem row norms
        rownorm_kernel<<<N_, 128, 0, stream>>>(mem, invn);
        // 4. r = wr @ mem
        gemm_nn<32, 32, EpiStoreR><<<dim3(M_ / 32, B_ / 32), 256, 0, stream>>>(
            wr, N_, mem, M_, N_, M_, EpiStoreR{r});
        // 5. h = tanh(xwx_t + r @ Wr + bh)
        gemm_nn<32, 32, EpiH><<<dim3(H_ / 32, B_ / 32), 256, 0, stream>>>(
            r, M_, Wr, H_, M_, H_, EpiH{xwx + (size_t)t * B_ * H_, bh, h});
        // 6. head projections p = h @ Wh + b (write head rows 0..255, read head 256..511)
        gemm_nn<32, 64, EpiP><<<dim3((M_ + 6 + 63) / 64, B_ / 32), 256, 0, stream>>>(
            h, H_, Whw, M_ + 6, H_, M_ + 6, EpiP{bhw, p});
        gemm_nn<32, 64, EpiP><<<dim3((M_ + 6 + 63) / 64, B_ / 32), 256, 0, stream>>>(
            h, H_, Whr, M_ + 6, H_, M_ + 6, EpiP{bhr, p + (size_t)B_ * (M_ + 6)});
        // 7. per-row head scalars + k normalization
        headscal_kernel<<<2 * B_, 128, 0, stream>>>(p, kh, rowsc, params);
        // 8. scores = kh @ mem^T
        gemm_scores<<<dim3(N_ / 64, 2 * B_ / 64), 256, 0, stream>>>(kh, mem, scores);
        // 9. addressing tail -> ww, wr updated in place
        addr_kernel<<<2 * B_, 256, 0, stream>>>(scores, invn, rowsc, params, ww, wr);
        // 10. out[:, t, :] = sigmoid(h @ Wo + bo)
        gemm_nn<32, 32, EpiOut><<<dim3(O_ / 32, B_ / 32), 256, 0, stream>>>(
            h, H_, Wo, O_, H_, O_, EpiOut{bo, out + (size_t)t * O_});
    }
}

// Round 2
// 21282.739 us; speedup vs baseline: 1.7845x; 1.7845x over previous
//
#include <hip/hip_runtime.h>
#include <math.h>

// NTM recurrence. All GEMMs via 6-term bf16-split MFMA (fp32-equivalent precision).
// B=256 T=128 I=512 H=512 N=1024 M=512 O=512
#define B_ 256
#define T_ 128
#define I_ 512
#define H_ 512
#define N_ 1024
#define M_ 512
#define O_ 512
#define EPS_ 1e-8f

typedef unsigned short u16;
typedef __attribute__((ext_vector_type(8))) short v8s;   // 8 bf16 = 4 VGPRs
typedef __attribute__((ext_vector_type(4))) float v4f;   // MFMA acc

#define MFMA(a, b, c) __builtin_amdgcn_mfma_f32_16x16x32_bf16(a, b, c, 0, 0, 0)

// plane strides (elements)
#define PL_WEA 524288   // WeaT [1024][512]
#define PL_WXT 262144   // WxT  [512][512]
#define PL_WRT 262144   // WrT  [512][512]
#define PL_WHK 524288   // WhKT [1024][512] (rows 0-511 Whw keys, 512-1023 Whr keys)
#define PL_WOT 262144   // WoT  [512][512]
#define PL_MEM 524288   // mem  [1024][512] / memT [512][1024]
#define PL_W   262144   // wwT [1024][256] / wr [256][1024]
#define PL_H   131072   // h [256][512], r [256][512], eT/aT [512][256]
#define PL_KH  262144   // kh [512][512]

// ---------------- scalar helpers ----------------
__device__ __forceinline__ float sigm_(float x) { return 1.f / (1.f + expf(-x)); }
__device__ __forceinline__ float softplus_(float x) { return x > 20.f ? x : log1pf(expf(x)); }
__device__ __forceinline__ u16 f2bf(float f) {
    unsigned u = __float_as_uint(f);
    u += 0x7fffu + ((u >> 16) & 1u);
    return (u16)(u >> 16);
}
__device__ __forceinline__ float bf2f(u16 h) { return __uint_as_float((unsigned)h << 16); }
__device__ __forceinline__ void split3(float f, u16& h, u16& m, u16& l) {
    h = f2bf(f);
    float r1 = f - bf2f(h);
    m = f2bf(r1);
    float r2 = r1 - bf2f(m);
    l = f2bf(r2);
}

__device__ __forceinline__ float wave_sum_(float v) {
#pragma unroll
    for (int o = 32; o > 0; o >>= 1) v += __shfl_down(v, o);
    return v;
}
__device__ __forceinline__ float wave_max_(float v) {
#pragma unroll
    for (int o = 32; o > 0; o >>= 1) v = fmaxf(v, __shfl_down(v, o));
    return v;
}
__device__ float block_sum_(float v, float* s) {
    int lane = threadIdx.x & 63, wid = threadIdx.x >> 6, nw = blockDim.x >> 6;
    v = wave_sum_(v);
    if (lane == 0) s[wid] = v;
    __syncthreads();
    float r = (threadIdx.x < nw) ? s[threadIdx.x] : 0.f;
    if (wid == 0) { r = wave_sum_(r); if (lane == 0) s[0] = r; }
    __syncthreads();
    float out = s[0];
    __syncthreads();
    return out;
}
__device__ float block_max_(float v, float* s) {
    int lane = threadIdx.x & 63, wid = threadIdx.x >> 6, nw = blockDim.x >> 6;
    v = wave_max_(v);
    if (lane == 0) s[wid] = v;
    __syncthreads();
    float r = (threadIdx.x < nw) ? s[threadIdx.x] : -3.4e38f;
    if (wid == 0) { r = wave_max_(r); if (lane == 0) s[0] = r; }
    __syncthreads();
    float out = s[0];
    __syncthreads();
    return out;
}

// ---------------- epilogues (called per 16x16 C-tile fragment: 4 rows r0..r0+3, col c) ----------------
struct EpiEA {  // C'[m(1024)][b]: m<512 -> e=sigmoid, else a=tanh; + bea[m]; write eT/aT planes
    const float* bea; u16* eT; u16* aT;
    __device__ void operator()(int r0, int c, v4f v) const {
#pragma unroll
        for (int r = 0; r < 4; r++) {
            int m = r0 + r;
            float val = v[r] + bea[m];
            u16 *dst;
            if (m < M_) { val = sigm_(val); dst = eT + (size_t)m * B_ + c; }
            else        { val = tanhf(val); dst = aT + (size_t)(m - M_) * B_ + c; }
            u16 h, mm, l; split3(val, h, mm, l);
            dst[0] = h; dst[PL_H] = mm; dst[2 * PL_H] = l;
        }
    }
};
struct EpiR {  // C[b][m] -> r planes
    u16* rp;
    __device__ void operator()(int r0, int c, v4f v) const {
#pragma unroll
        for (int r = 0; r < 4; r++) {
            u16 h, m, l; split3(v[r], h, m, l);
            size_t idx = (size_t)(r0 + r) * M_ + c;
            rp[idx] = h; rp[PL_H + idx] = m; rp[2 * PL_H + idx] = l;
        }
    }
};
struct EpiH {  // C[b][hdim] + xwx(in d_out layout) + bh -> tanh -> h_f32 + planes
    const float* xwxt; const float* bh; float* hf; u16* hp;
    __device__ void operator()(int r0, int c, v4f v) const {
#pragma unroll
        for (int r = 0; r < 4; r++) {
            int b = r0 + r;
            float val = tanhf(v[r] + xwxt[(size_t)b * (T_ * O_) + c] + bh[c]);
            size_t idx = (size_t)b * H_ + c;
            hf[idx] = val;
            u16 h, m, l; split3(val, h, m, l);
            hp[idx] = h; hp[PL_H + idx] = m; hp[2 * PL_H + idx] = l;
        }
    }
};
struct EpiKeys {  // C[b][headkey(1024)]: head=c>>9 -> kh[head*256+b][key] = tanh(v+bias)
    const float* bhw; const float* bhr; u16* khp;
    __device__ void operator()(int r0, int c, v4f v) const {
        int head = c >> 9, key = c & 511;
        const float* bb = head ? bhr : bhw;
#pragma unroll
        for (int r = 0; r < 4; r++) {
            float val = tanhf(v[r] + bb[key]);
            size_t idx = (size_t)(head * 256 + r0 + r) * M_ + key;
            u16 h, m, l; split3(val, h, m, l);
            khp[idx] = h; khp[PL_KH + idx] = m; khp[2 * PL_KH + idx] = l;
        }
    }
};
struct EpiScore {  // C[row(512)][n(1024)] * invn[n] * rowscale[row] -> logits
    const float* invn; const float* rowsc; float* logits;
    __device__ void operator()(int r0, int c, v4f v) const {
        float in_ = invn[c];
#pragma unroll
        for (int r = 0; r < 4; r++)
            logits[(size_t)(r0 + r) * N_ + c] = v[r] * in_ * rowsc[r0 + r];
    }
};
struct EpiOut {  // C[b][o] -> sigmoid(v+bo) -> out[b][t][o]
    const float* bo; float* outt;
    __device__ void operator()(int r0, int c, v4f v) const {
#pragma unroll
        for (int r = 0; r < 4; r++)
            outt[(size_t)(r0 + r) * (T_ * O_) + c] = sigm_(v[r] + bo[c]);
    }
};

// ---------------- generic 6-term MFMA GEMM ----------------
// A planes row-major [M][K] (lda), B planes = B^T row-major [N][K] (ldb). BM=BN=64, BK=32.
// 256 threads = 4 waves (2x2), wave tile 32x32 via 2x2 MFMA 16x16x32 tiles.
template <class Epi>
__global__ __launch_bounds__(256) void gemm6(const u16* __restrict__ Ap, int lda, int apl,
                                             const u16* __restrict__ Bp, int ldb, int bpl,
                                             int K, Epi epi) {
    __shared__ u16 As[3][64][40];
    __shared__ u16 Bs[3][64][40];
    const int tid = threadIdx.x, lane = tid & 63, w = tid >> 6;
    const int wy = w >> 1, wx = w & 1, q = lane >> 4, l15 = lane & 15;
    const int row0 = blockIdx.y * 64, col0 = blockIdx.x * 64;
    const int sr = tid >> 2, ss = (tid & 3) * 8;
    v4f acc[2][2] = {};
    const u16* Ab = Ap + (size_t)(row0 + sr) * lda + ss;
    const u16* Bb = Bp + (size_t)(col0 + sr) * ldb + ss;
    for (int k0 = 0; k0 < K; k0 += 32) {
#pragma unroll
        for (int p = 0; p < 3; p++) {
            *(uint4*)&As[p][sr][ss] = *(const uint4*)(Ab + (size_t)p * apl + k0);
            *(uint4*)&Bs[p][sr][ss] = *(const uint4*)(Bb + (size_t)p * bpl + k0);
        }
        __syncthreads();
        v8s af[2][3], bf[2][3];
#pragma unroll
        for (int mt = 0; mt < 2; mt++)
#pragma unroll
            for (int p = 0; p < 3; p++) {
                af[mt][p] = *(const v8s*)&As[p][wy * 32 + mt * 16 + l15][q * 8];
                bf[mt][p] = *(const v8s*)&Bs[p][wx * 32 + mt * 16 + l15][q * 8];
            }
#pragma unroll
        for (int mt = 0; mt < 2; mt++)
#pragma unroll
            for (int nt = 0; nt < 2; nt++) {
                v4f c = acc[mt][nt];
                c = MFMA(af[mt][0], bf[nt][0], c);
                c = MFMA(af[mt][0], bf[nt][1], c);
                c = MFMA(af[mt][1], bf[nt][0], c);
                c = MFMA(af[mt][0], bf[nt][2], c);
                c = MFMA(af[mt][2], bf[nt][0], c);
                c = MFMA(af[mt][1], bf[nt][1], c);
                acc[mt][nt] = c;
            }
        __syncthreads();
    }
#pragma unroll
    for (int mt = 0; mt < 2; mt++)
#pragma unroll
        for (int nt = 0; nt < 2; nt++)
            epi(row0 + wy * 32 + mt * 16 + q * 4, col0 + wx * 32 + nt * 16 + l15, acc[mt][nt]);
}

// ---------------- dual-B memupd: Se=wwT@eT^T, Sa=wwT@aT^T; mem=mem*(1-Se/B)+Sa/B ----------------
__global__ __launch_bounds__(256) void memupd6(const u16* __restrict__ wwT, const u16* __restrict__ eT,
                                               const u16* __restrict__ aT, float* __restrict__ memf,
                                               u16* __restrict__ mem_pl, u16* __restrict__ memT_pl) {
    __shared__ u16 As[3][64][40], Be[3][64][40], Ba[3][64][40];
    const int tid = threadIdx.x, lane = tid & 63, w = tid >> 6;
    const int wy = w >> 1, wx = w & 1, q = lane >> 4, l15 = lane & 15;
    const int row0 = blockIdx.y * 64, col0 = blockIdx.x * 64;  // row=n, col=m
    const int sr = tid >> 2, ss = (tid & 3) * 8;
    v4f ae[2][2] = {}, aa[2][2] = {};
    for (int k0 = 0; k0 < B_; k0 += 32) {
#pragma unroll
        for (int p = 0; p < 3; p++) {
            *(uint4*)&As[p][sr][ss] = *(const uint4*)&wwT[(size_t)p * PL_W + (size_t)(row0 + sr) * B_ + k0 + ss];
            *(uint4*)&Be[p][sr][ss] = *(const uint4*)&eT[(size_t)p * PL_H + (size_t)(col0 + sr) * B_ + k0 + ss];
            *(uint4*)&Ba[p][sr][ss] = *(const uint4*)&aT[(size_t)p * PL_H + (size_t)(col0 + sr) * B_ + k0 + ss];
        }
        __syncthreads();
        v8s af[2][3], be[2][3], ba[2][3];
#pragma unroll
        for (int mt = 0; mt < 2; mt++)
#pragma unroll
            for (int p = 0; p < 3; p++) {
                af[mt][p] = *(const v8s*)&As[p][wy * 32 + mt * 16 + l15][q * 8];
                be[mt][p] = *(const v8s*)&Be[p][wx * 32 + mt * 16 + l15][q * 8];
                ba[mt][p] = *(const v8s*)&Ba[p][wx * 32 + mt * 16 + l15][q * 8];
            }
#pragma unroll
        for (int mt = 0; mt < 2; mt++)
#pragma unroll
            for (int nt = 0; nt < 2; nt++) {
                v4f c = ae[mt][nt];
                c = MFMA(af[mt][0], be[nt][0], c);
                c = MFMA(af[mt][0], be[nt][1], c);
                c = MFMA(af[mt][1], be[nt][0], c);
                c = MFMA(af[mt][0], be[nt][2], c);
                c = MFMA(af[mt][2], be[nt][0], c);
                c = MFMA(af[mt][1], be[nt][1], c);
                ae[mt][nt] = c;
                v4f d2 = aa[mt][nt];
                d2 = MFMA(af[mt][0], ba[nt][0], d2);
                d2 = MFMA(af[mt][0], ba[nt][1], d2);
                d2 = MFMA(af[mt][1], ba[nt][0], d2);
                d2 = MFMA(af[mt][0], ba[nt][2], d2);
                d2 = MFMA(af[mt][2], ba[nt][0], d2);
                d2 = MFMA(af[mt][1], ba[nt][1], d2);
                aa[mt][nt] = d2;
            }
        __syncthreads();
    }
    const float invB = 1.f / (float)B_;
#pragma unroll
    for (int mt = 0; mt < 2; mt++)
#pragma unroll
        for (int nt = 0; nt < 2; nt++) {
            int r0 = row0 + wy * 32 + mt * 16 + q * 4;
            int c  = col0 + wx * 32 + nt * 16 + l15;
            u16 hv[4][3];
#pragma unroll
            for (int r = 0; r < 4; r++) {
                size_t idx = (size_t)(r0 + r) * M_ + c;
                float old = memf[idx];
                float nv = old * (1.f - ae[mt][nt][r] * invB) + aa[mt][nt][r] * invB;
                memf[idx] = nv;
                u16 h, m2, l; split3(nv, h, m2, l);
                mem_pl[idx] = h; mem_pl[PL_MEM + idx] = m2; mem_pl[2 * PL_MEM + idx] = l;
                hv[r][0] = h; hv[r][1] = m2; hv[r][2] = l;
            }
            size_t tb = (size_t)c * N_ + r0;
#pragma unroll
            for (int p = 0; p < 3; p++)
                *(ushort4*)&memT_pl[(size_t)p * PL_MEM + tb] =
                    make_ushort4(hv[0][p], hv[1][p], hv[2][p], hv[3][p]);
        }
}

// ---------------- xwx GEMM: rows (t*256+b), A from x f32 (split on the fly), out -> d_out[b][t][:] ----------------
__global__ __launch_bounds__(256) void gemm6_xwx(const float* __restrict__ x, const u16* __restrict__ WxT,
                                                 float* __restrict__ outbuf) {
    __shared__ u16 As[3][64][40];
    __shared__ u16 Bs[3][64][40];
    const int tid = threadIdx.x, lane = tid & 63, w = tid >> 6;
    const int wy = w >> 1, wx = w & 1, q = lane >> 4, l15 = lane & 15;
    const int row0 = blockIdx.y * 64, col0 = blockIdx.x * 64;
    const int sr = tid >> 2, ss = (tid & 3) * 8;
    const int arow = row0 + sr, ab = arow & 255, at = arow >> 8;
    const float* Asrc = x + ((size_t)ab * T_ + at) * I_ + ss;
    v4f acc[2][2] = {};
    for (int k0 = 0; k0 < I_; k0 += 32) {
        float4 f0 = *(const float4*)(Asrc + k0);
        float4 f1 = *(const float4*)(Asrc + k0 + 4);
        float av8[8] = {f0.x, f0.y, f0.z, f0.w, f1.x, f1.y, f1.z, f1.w};
#pragma unroll
        for (int j = 0; j < 8; j++) {
            u16 h, m, l; split3(av8[j], h, m, l);
            As[0][sr][ss + j] = h; As[1][sr][ss + j] = m; As[2][sr][ss + j] = l;
        }
#pragma unroll
        for (int p = 0; p < 3; p++)
            *(uint4*)&Bs[p][sr][ss] = *(const uint4*)&WxT[(size_t)p * PL_WXT + (size_t)(col0 + sr) * I_ + k0 + ss];
        __syncthreads();
        v8s af[2][3], bf[2][3];
#pragma unroll
        for (int mt = 0; mt < 2; mt++)
#pragma unroll
            for (int p = 0; p < 3; p++) {
                af[mt][p] = *(const v8s*)&As[p][wy * 32 + mt * 16 + l15][q * 8];
                bf[mt][p] = *(const v8s*)&Bs[p][wx * 32 + mt * 16 + l15][q * 8];
            }
#pragma unroll
        for (int mt = 0; mt < 2; mt++)
#pragma unroll
            for (int nt = 0; nt < 2; nt++) {
                v4f c = acc[mt][nt];
                c = MFMA(af[mt][0], bf[nt][0], c);
                c = MFMA(af[mt][0], bf[nt][1], c);
                c = MFMA(af[mt][1], bf[nt][0], c);
                c = MFMA(af[mt][0], bf[nt][2], c);
                c = MFMA(af[mt][2], bf[nt][0], c);
                c = MFMA(af[mt][1], bf[nt][1], c);
                acc[mt][nt] = c;
            }
        __syncthreads();
    }
#pragma unroll
    for (int mt = 0; mt < 2; mt++)
#pragma unroll
        for (int nt = 0; nt < 2; nt++) {
            int r0 = row0 + wy * 32 + mt * 16 + q * 4;
            int c  = col0 + wx * 32 + nt * 16 + l15;
#pragma unroll
            for (int r = 0; r < 4; r++) {
                int row = r0 + r, b = row & 255, t = row >> 8;
                outbuf[((size_t)b * T_ + t) * O_ + c] = acc[mt][nt][r];
            }
        }
}

// ---------------- decomp: transpose + split weight: in f32 [R][ldin] cols c0.. -> planes [Cout][R] ----------------
__global__ __launch_bounds__(256) void decomp_t(const float* __restrict__ in, int ldin, int c0,
                                                int R, u16* __restrict__ outp, int opl) {
    __shared__ float Ls[32][33];
    const int r0 = blockIdx.x * 32, cB = blockIdx.y * 32;
    const int tid = threadIdx.x;
    int lr = tid >> 3, lc = (tid & 7) * 4;
#pragma unroll
    for (int j = 0; j < 4; j++)
        Ls[lr][lc + j] = in[(size_t)(r0 + lr) * ldin + c0 + cB + lc + j];
    __syncthreads();
    int lc2 = tid >> 3, lr2 = (tid & 7) * 4;
    u16 hv[4], mv[4], lv[4];
#pragma unroll
    for (int j = 0; j < 4; j++) split3(Ls[lr2 + j][lc2], hv[j], mv[j], lv[j]);
    size_t base = (size_t)(cB + lc2) * R + r0 + lr2;
    *(ushort4*)&outp[0 * (size_t)opl + base] = make_ushort4(hv[0], hv[1], hv[2], hv[3]);
    *(ushort4*)&outp[1 * (size_t)opl + base] = make_ushort4(mv[0], mv[1], mv[2], mv[3]);
    *(ushort4*)&outp[2 * (size_t)opl + base] = make_ushort4(lv[0], lv[1], lv[2], lv[3]);
}

// ---------------- small kernels ----------------
__global__ __launch_bounds__(512) void wh6_kernel(const float* __restrict__ Whw, const float* __restrict__ Whr,
                                                  float* __restrict__ w6w, float* __restrict__ w6r) {
    int k = threadIdx.x;
    const float* src = blockIdx.x ? Whr : Whw;
    float* dst = blockIdx.x ? w6r : w6w;
#pragma unroll
    for (int j = 0; j < 6; j++) dst[k * 6 + j] = src[(size_t)k * (M_ + 6) + M_ + j];
}

__global__ __launch_bounds__(256) void init_mem(const float* __restrict__ mem0, float* __restrict__ memf,
                                                u16* __restrict__ mem_pl, u16* __restrict__ memT_pl) {
    int n = blockIdx.x;
    for (int c = threadIdx.x; c < M_; c += 256) {
        float v = mem0[(size_t)n * M_ + c];
        size_t idx = (size_t)n * M_ + c;
        memf[idx] = v;
        u16 h, m, l; split3(v, h, m, l);
        mem_pl[idx] = h; mem_pl[PL_MEM + idx] = m; mem_pl[2 * PL_MEM + idx] = l;
        size_t tb = (size_t)c * N_ + n;
        memT_pl[tb] = h; memT_pl[PL_MEM + tb] = m; memT_pl[2 * PL_MEM + tb] = l;
    }
}
__global__ __launch_bounds__(256) void init_w(const float* __restrict__ wr0, const float* __restrict__ ww0,
                                              float* __restrict__ wrf, float* __restrict__ wwf,
                                              u16* __restrict__ wr_pl, u16* __restrict__ wwT_pl) {
    int b = blockIdx.x;
    for (int n = threadIdx.x; n < N_; n += 256) {
        size_t idx = (size_t)b * N_ + n;
        float vw = ww0[idx]; wwf[idx] = vw;
        u16 h, m, l; split3(vw, h, m, l);
        size_t tb = (size_t)n * B_ + b;
        wwT_pl[tb] = h; wwT_pl[PL_W + tb] = m; wwT_pl[2 * PL_W + tb] = l;
        float vr = wr0[idx]; wrf[idx] = vr;
        split3(vr, h, m, l);
        wr_pl[idx] = h; wr_pl[PL_W + idx] = m; wr_pl[2 * PL_W + idx] = l;
    }
}
__global__ __launch_bounds__(64) void init_h(const float* __restrict__ h0, float* __restrict__ hf,
                                             u16* __restrict__ hp) {
    int b = blockIdx.x;
    for (int c = threadIdx.x; c < H_; c += 64) {
        size_t idx = (size_t)b * H_ + c;
        float v = h0[idx];
        hf[idx] = v;
        u16 h, m, l; split3(v, h, m, l);
        hp[idx] = h; hp[PL_H + idx] = m; hp[2 * PL_H + idx] = l;
    }
}

__global__ __launch_bounds__(64) void rownorm_k(const float* __restrict__ memf, float* __restrict__ invn) {
    int n = blockIdx.x;
    float s = 0.f;
    for (int i = threadIdx.x; i < M_; i += 64) { float v = memf[(size_t)n * M_ + i]; s += v * v; }
    s = wave_sum_(s);
    if (threadIdx.x == 0) invn[n] = 1.f / (sqrtf(s) + EPS_);
}

__global__ __launch_bounds__(64) void pscal_k(const float* __restrict__ hf, const float* __restrict__ w6w,
                                              const float* __restrict__ w6r, const float* __restrict__ bhw,
                                              const float* __restrict__ bhr, const u16* __restrict__ khp,
                                              float* __restrict__ rowsc, float* __restrict__ params) {
    int row = blockIdx.x, head = row >> 8, b = row & 255;
    const float* w6 = head ? w6r : w6w;
    const float* bias = head ? bhr : bhw;
    int lane = threadIdx.x;
    float d[6] = {0, 0, 0, 0, 0, 0};
    float ssq = 0.f;
#pragma unroll
    for (int j = 0; j < 8; j++) {
        int k = lane * 8 + j;
        float hv = hf[(size_t)b * H_ + k];
#pragma unroll
        for (int jc = 0; jc < 6; jc++) d[jc] += hv * w6[k * 6 + jc];
        size_t ki = (size_t)row * M_ + k;
        float kv = bf2f(khp[ki]) + bf2f(khp[PL_KH + ki]) + bf2f(khp[2 * PL_KH + ki]);
        ssq += kv * kv;
    }
#pragma unroll
    for (int o = 32; o > 0; o >>= 1) {
#pragma unroll
        for (int jc = 0; jc < 6; jc++) d[jc] += __shfl_down(d[jc], o);
        ssq += __shfl_down(ssq, o);
    }
    if (lane == 0) {
        float beta = softplus_(d[0] + bias[M_]);
        float g = sigm_(d[1] + bias[M_ + 1]);
        float a0 = d[2] + bias[M_ + 2], a1 = d[3] + bias[M_ + 3], a2 = d[4] + bias[M_ + 4];
        float mx = fmaxf(a0, fmaxf(a1, a2));
        float e0 = expf(a0 - mx), e1 = expf(a1 - mx), e2 = expf(a2 - mx);
        float es = e0 + e1 + e2;
        float gamma = 1.f + softplus_(d[5] + bias[M_ + 5]);
        rowsc[row] = beta / (sqrtf(ssq) + EPS_);
        params[row * 8 + 0] = g;
        params[row * 8 + 1] = e0 / es;
        params[row * 8 + 2] = e1 / es;
        params[row * 8 + 3] = e2 / es;
        params[row * 8 + 4] = gamma;
    }
}

// softmax -> interpolate -> shift -> sharpen -> normalize; write masters + planes
__global__ __launch_bounds__(256) void addr_k(const float* __restrict__ logits, const float* __restrict__ params,
                                              float* __restrict__ wwf, float* __restrict__ wrf,
                                              u16* __restrict__ wwT_pl, u16* __restrict__ wr_pl) {
    __shared__ float wgs[N_];
    __shared__ float red[8];
    int row = blockIdx.x, head = row >> 8, b = row & 255;
    float* wf = head ? wrf : wwf;
    const float* pr = params + row * 8;
    float g = pr[0], s0 = pr[1], s1 = pr[2], s2 = pr[3], gamma = pr[4];
    int tid = threadIdx.x;
    float l[4];
#pragma unroll
    for (int j = 0; j < 4; j++) l[j] = logits[(size_t)row * N_ + tid * 4 + j];
    float mx = fmaxf(fmaxf(l[0], l[1]), fmaxf(l[2], l[3]));
    mx = block_max_(mx, red);
    float ex[4], sum = 0.f;
#pragma unroll
    for (int j = 0; j < 4; j++) { ex[j] = expf(l[j] - mx); sum += ex[j]; }
    sum = block_sum_(sum, red);
    float inv = 1.f / sum;
    float wprev[4];
#pragma unroll
    for (int j = 0; j < 4; j++) wprev[j] = wf[(size_t)b * N_ + tid * 4 + j];
#pragma unroll
    for (int j = 0; j < 4; j++) wgs[tid * 4 + j] = g * ex[j] * inv + (1.f - g) * wprev[j];
    __syncthreads();
    float wp[4], psum = 0.f;
#pragma unroll
    for (int j = 0; j < 4; j++) {
        int n = tid * 4 + j;
        float wt = s0 * wgs[(n + 1) & (N_ - 1)] + s1 * wgs[n] + s2 * wgs[(n - 1) & (N_ - 1)];
        float v = expf(gamma * logf(wt));
        wp[j] = v; psum += v;
    }
    psum = block_sum_(psum, red);
    float invp = 1.f / (psum + EPS_);
#pragma unroll
    for (int j = 0; j < 4; j++) {
        int n = tid * 4 + j;
        float val = wp[j] * invp;
        wf[(size_t)b * N_ + n] = val;
        u16 h, m, lo; split3(val, h, m, lo);
        if (head == 0) {
            size_t tb = (size_t)n * B_ + b;
            wwT_pl[tb] = h; wwT_pl[PL_W + tb] = m; wwT_pl[2 * PL_W + tb] = lo;
        } else {
            size_t idx = (size_t)b * N_ + n;
            wr_pl[idx] = h; wr_pl[PL_W + idx] = m; wr_pl[2 * PL_W + idx] = lo;
        }
    }
}

// ---------------- host ----------------
extern "C" void kernel_launch(void* const* d_in, const int* in_sizes, int n_in,
                              void* d_out, int out_size, void* d_ws, size_t ws_size,
                              hipStream_t stream) {
    (void)in_sizes; (void)n_in; (void)out_size; (void)ws_size;
    const float* x    = (const float*)d_in[0];
    const float* mem0 = (const float*)d_in[1];
    const float* wr0  = (const float*)d_in[2];
    const float* ww0  = (const float*)d_in[3];
    const float* h0   = (const float*)d_in[4];
    const float* Wx   = (const float*)d_in[5];
    const float* Wr   = (const float*)d_in[6];
    const float* bh   = (const float*)d_in[7];
    const float* Whr  = (const float*)d_in[8];
    const float* bhr  = (const float*)d_in[9];
    const float* Whw  = (const float*)d_in[10];
    const float* bhw  = (const float*)d_in[11];
    const float* Wea  = (const float*)d_in[12];
    const float* bea  = (const float*)d_in[13];
    const float* Wo   = (const float*)d_in[14];
    const float* bo   = (const float*)d_in[15];
    float* out = (float*)d_out;

    // ---- carve workspace ----
    char* wsb = (char*)d_ws;
    size_t off = 0;
    auto carveU = [&](size_t elems) { u16* p = (u16*)(wsb + off); off += elems * sizeof(u16); return p; };
    u16* WeaT  = carveU(3 * (size_t)PL_WEA);
    u16* WxT   = carveU(3 * (size_t)PL_WXT);
    u16* WrT   = carveU(3 * (size_t)PL_WRT);
    u16* WhKT  = carveU(3 * (size_t)PL_WHK);
    u16* WoT   = carveU(3 * (size_t)PL_WOT);
    u16* mem_pl  = carveU(3 * (size_t)PL_MEM);
    u16* memT_pl = carveU(3 * (size_t)PL_MEM);
    u16* wwT_pl  = carveU(3 * (size_t)PL_W);
    u16* wr_pl   = carveU(3 * (size_t)PL_W);
    u16* h_pl    = carveU(3 * (size_t)PL_H);
    u16* r_pl    = carveU(3 * (size_t)PL_H);
    u16* eT_pl   = carveU(3 * (size_t)PL_H);
    u16* aT_pl   = carveU(3 * (size_t)PL_H);
    u16* kh_pl   = carveU(3 * (size_t)PL_KH);
    auto carveF = [&](size_t elems) { float* p = (float*)(wsb + off); off += elems * sizeof(float); return p; };
    float* memf   = carveF((size_t)N_ * M_);
    float* wwf    = carveF((size_t)B_ * N_);
    float* wrf    = carveF((size_t)B_ * N_);
    float* hf     = carveF((size_t)B_ * H_);
    float* logits = carveF((size_t)2 * B_ * N_);
    float* w6w    = carveF(H_ * 6);
    float* w6r    = carveF(H_ * 6);
    float* invn   = carveF(N_);
    float* rowsc  = carveF(2 * B_);
    float* params = carveF(2 * B_ * 8);

    // ---- once-per-call: weight decompositions + state init ----
    decomp_t<<<dim3(512 / 32, 1024 / 32), 256, 0, stream>>>(Wea, 1024, 0, 512, WeaT, PL_WEA);
    decomp_t<<<dim3(512 / 32, 512 / 32), 256, 0, stream>>>(Wx, 512, 0, 512, WxT, PL_WXT);
    decomp_t<<<dim3(512 / 32, 512 / 32), 256, 0, stream>>>(Wr, 512, 0, 512, WrT, PL_WRT);
    decomp_t<<<dim3(512 / 32, 512 / 32), 256, 0, stream>>>(Whw, M_ + 6, 0, 512, WhKT, PL_WHK);
    decomp_t<<<dim3(512 / 32, 512 / 32), 256, 0, stream>>>(Whr, M_ + 6, 0, 512, WhKT + (size_t)512 * 512, PL_WHK);
    decomp_t<<<dim3(512 / 32, 512 / 32), 256, 0, stream>>>(Wo, 512, 0, 512, WoT, PL_WOT);
    wh6_kernel<<<2, 512, 0, stream>>>(Whw, Whr, w6w, w6r);
    init_mem<<<N_, 256, 0, stream>>>(mem0, memf, mem_pl, memT_pl);
    init_w<<<B_, 256, 0, stream>>>(wr0, ww0, wrf, wwf, wr_pl, wwT_pl);
    init_h<<<B_, 64, 0, stream>>>(h0, hf, h_pl);

    // xwx for all (t,b) -> stored in d_out slots [b][t][:] (consumed by EpiH before EpiOut overwrites)
    gemm6_xwx<<<dim3(H_ / 64, (T_ * B_) / 64), 256, 0, stream>>>(x, WxT, out);

    for (int t = 0; t < T_; t++) {
        // 1. eaT = (h @ Wea)^T with sigmoid/tanh -> eT, aT planes   [M=1024(m), N=256(b), K=512]
        gemm6<EpiEA><<<dim3(B_ / 64, 1024 / 64), 256, 0, stream>>>(
            WeaT, 512, PL_WEA, h_pl, 512, PL_H, 512, EpiEA{bea, eT_pl, aT_pl});
        // 2. mem update  [M=1024(n), N=512(m), K=256]
        memupd6<<<dim3(M_ / 64, N_ / 64), 256, 0, stream>>>(wwT_pl, eT_pl, aT_pl, memf, mem_pl, memT_pl);
        // 3. mem row inverse norms
        rownorm_k<<<N_, 64, 0, stream>>>(memf, invn);
        // 4. r = wr @ mem  [M=256(b), N=512(m), K=1024]
        gemm6<EpiR><<<dim3(M_ / 64, B_ / 64), 256, 0, stream>>>(
            wr_pl, 1024, PL_W, memT_pl, 1024, PL_MEM, 1024, EpiR{r_pl});
        // 5. h = tanh(xwx + r @ Wr + bh)  [M=256(b), N=512(h), K=512]
        gemm6<EpiH><<<dim3(H_ / 64, B_ / 64), 256, 0, stream>>>(
            r_pl, 512, PL_H, WrT, 512, PL_WRT, 512, EpiH{out + (size_t)t * O_, bh, hf, h_pl});
        // 6. kh = tanh(h @ [Whw_k | Whr_k] + bias)  [M=256(b), N=1024(head,key), K=512]
        gemm6<EpiKeys><<<dim3(1024 / 64, B_ / 64), 256, 0, stream>>>(
            h_pl, 512, PL_H, WhKT, 512, PL_WHK, 512, EpiKeys{bhw, bhr, kh_pl});
        // 7. per-row scalars (beta,g,s,gamma) + ||k||
        pscal_k<<<2 * B_, 64, 0, stream>>>(hf, w6w, w6r, bhw, bhr, kh_pl, rowsc, params);
        // 8. logits = (kh @ mem^T) * invn * rowscale  [M=512(row), N=1024(n), K=512]
        gemm6<EpiScore><<<dim3(N_ / 64, 512 / 64), 256, 0, stream>>>(
            kh_pl, 512, PL_KH, mem_pl, 512, PL_MEM, 512, EpiScore{invn, rowsc, logits});
        // 9. addressing tail -> ww/wr masters + planes
        addr_k<<<2 * B_, 256, 0, stream>>>(logits, params, wwf, wrf, wwT_pl, wr_pl);
        // 10. out[:, t, :] = sigmoid(h @ Wo + bo)  [M=256(b), N=512(o), K=512]
        gemm6<EpiOut><<<dim3(O_ / 64, B_ / 64), 256, 0, stream>>>(
            h_pl, 512, PL_H, WoT, 512, PL_WOT, 512, EpiOut{bo, out + (size_t)t * O_});
    }
}

// Round 3
// 17678.853 us; speedup vs baseline: 2.1482x; 1.2039x over previous
//
#include <hip/hip_runtime.h>
#include <math.h>

// NTM recurrence. GEMMs via 3-product 2-plane bf16-split MFMA (~2^-17 rel err per GEMM,
// fp32 state masters). Fused per-step schedule: 6 dispatches/step.
// B=256 T=128 I=512 H=512 N=1024 M=512 O=512
#define B_ 256
#define T_ 128
#define I_ 512
#define H_ 512
#define N_ 1024
#define M_ 512
#define O_ 512
#define EPS_ 1e-8f

typedef unsigned short u16;
typedef __attribute__((ext_vector_type(8))) short v8s;   // 8 bf16 = 4 VGPRs
typedef __attribute__((ext_vector_type(4))) float v4f;   // MFMA acc

#define MFMA(a, b, c) __builtin_amdgcn_mfma_f32_16x16x32_bf16(a, b, c, 0, 0, 0)

// plane strides (elements)
#define PL_BIG 1310720  // BigT [2560][512]: rows 0-511 Whw_k, 512-1023 Whr_k, 1024-1535 Wo, 1536-2559 Wea
#define PL_WXT 262144   // WxT  [512][512]
#define PL_WRT 262144   // WrT  [512][512]
#define PL_MEM 524288   // mem  [1024][512] / memT [512][1024]
#define PL_W   262144   // wwT [1024][256] / wr [256][1024]
#define PL_H   131072   // h [256][512], r [256][512], eT/aT [512][256]
#define PL_KH  262144   // kh [512][512]

// ---------------- scalar helpers ----------------
__device__ __forceinline__ float sigm_(float x) { return 1.f / (1.f + expf(-x)); }
__device__ __forceinline__ float softplus_(float x) { return x > 20.f ? x : log1pf(expf(x)); }
__device__ __forceinline__ u16 f2bf(float f) {
    unsigned u = __float_as_uint(f);
    u += 0x7fffu + ((u >> 16) & 1u);
    return (u16)(u >> 16);
}
__device__ __forceinline__ float bf2f(u16 h) { return __uint_as_float((unsigned)h << 16); }
__device__ __forceinline__ void split2(float f, u16& h, u16& m) {
    h = f2bf(f);
    m = f2bf(f - bf2f(h));
}

__device__ __forceinline__ float wave_sum_(float v) {
#pragma unroll
    for (int o = 32; o > 0; o >>= 1) v += __shfl_down(v, o);
    return v;
}
__device__ __forceinline__ float wave_max_(float v) {
#pragma unroll
    for (int o = 32; o > 0; o >>= 1) v = fmaxf(v, __shfl_down(v, o));
    return v;
}
__device__ float block_sum_(float v, float* s) {
    int lane = threadIdx.x & 63, wid = threadIdx.x >> 6, nw = blockDim.x >> 6;
    v = wave_sum_(v);
    if (lane == 0) s[wid] = v;
    __syncthreads();
    float r = (threadIdx.x < nw) ? s[threadIdx.x] : 0.f;
    if (wid == 0) { r = wave_sum_(r); if (lane == 0) s[0] = r; }
    __syncthreads();
    float out = s[0];
    __syncthreads();
    return out;
}
__device__ float block_max_(float v, float* s) {
    int lane = threadIdx.x & 63, wid = threadIdx.x >> 6, nw = blockDim.x >> 6;
    v = wave_max_(v);
    if (lane == 0) s[wid] = v;
    __syncthreads();
    float r = (threadIdx.x < nw) ? s[threadIdx.x] : -3.4e38f;
    if (wid == 0) { r = wave_max_(r); if (lane == 0) s[0] = r; }
    __syncthreads();
    float out = s[0];
    __syncthreads();
    return out;
}

// ---------------- epilogues (per 16x16 fragment: rows r0..r0+3 (A-rows), col c (B-row)) ----------------
struct EpiEA0 {  // prologue ea only: r=b, c=m(0..1023)
    const float* bea; u16* eT; u16* aT;
    __device__ void operator()(int r0, int c, v4f v) const {
#pragma unroll
        for (int r = 0; r < 4; r++) {
            float val = v[r] + bea[c];
            u16* dst;
            int b = r0 + r;
            if (c < M_) { val = sigm_(val); dst = eT + (size_t)c * B_ + b; }
            else        { val = tanhf(val); dst = aT + (size_t)(c - M_) * B_ + b; }
            u16 h, m; split2(val, h, m);
            dst[0] = h; dst[PL_H] = m;
        }
    }
};
struct EpiR {  // C[b][m] -> r planes
    u16* rp;
    __device__ void operator()(int r0, int c, v4f v) const {
#pragma unroll
        for (int r = 0; r < 4; r++) {
            u16 h, m; split2(v[r], h, m);
            size_t idx = (size_t)(r0 + r) * M_ + c;
            rp[idx] = h; rp[PL_H + idx] = m;
        }
    }
};
struct EpiH {  // C[b][hdim] + xwx(in d_out layout) + bh -> tanh -> h_f32 + planes
    const float* xwxt; const float* bh; float* hf; u16* hp;
    __device__ void operator()(int r0, int c, v4f v) const {
#pragma unroll
        for (int r = 0; r < 4; r++) {
            int b = r0 + r;
            float val = tanhf(v[r] + xwxt[(size_t)b * (T_ * O_) + c] + bh[c]);
            size_t idx = (size_t)b * H_ + c;
            hf[idx] = val;
            u16 h, m; split2(val, h, m);
            hp[idx] = h; hp[PL_H + idx] = m;
        }
    }
};
struct EpiFused {  // c<1024: keys; 1024..1535: out; 1536..: ea(next step)
    const float* bhw; const float* bhr; const float* bo; const float* bea;
    u16* khp; float* outt; u16* eT; u16* aT;
    __device__ void operator()(int r0, int c, v4f v) const {
        if (c < 1024) {
            int head = c >> 9, key = c & 511;
            const float* bb = head ? bhr : bhw;
#pragma unroll
            for (int r = 0; r < 4; r++) {
                float val = tanhf(v[r] + bb[key]);
                size_t idx = (size_t)(head * 256 + r0 + r) * M_ + key;
                u16 h, m; split2(val, h, m);
                khp[idx] = h; khp[PL_KH + idx] = m;
            }
        } else if (c < 1536) {
            int o = c - 1024;
#pragma unroll
            for (int r = 0; r < 4; r++)
                outt[(size_t)(r0 + r) * (T_ * O_) + o] = sigm_(v[r] + bo[o]);
        } else {
            int m = c - 1536;
#pragma unroll
            for (int r = 0; r < 4; r++) {
                float val = v[r] + bea[m];
                u16* dst;
                int b = r0 + r;
                if (m < M_) { val = sigm_(val); dst = eT + (size_t)m * B_ + b; }
                else        { val = tanhf(val); dst = aT + (size_t)(m - M_) * B_ + b; }
                u16 h, mm; split2(val, h, mm);
                dst[0] = h; dst[PL_H] = mm;
            }
        }
    }
};

// ---------------- generic 3-product MFMA GEMM, reg-prefetch pipelined ----------------
// A planes row-major [M][K] (lda), B planes = B^T row-major [N][K] (ldb). Tile TM x 64, BK=32.
template <int TM, class Epi>
__global__ __launch_bounds__(256) void gemm2(const u16* __restrict__ Ap, int lda, int apl,
                                             const u16* __restrict__ Bp, int ldb, int bpl,
                                             int K, Epi epi) {
    constexpr int AL = (TM * 32 * 2) / (256 * 8);  // uint4 loads/thread for A
    constexpr int MT = TM / 32;
    __shared__ u16 As[2][TM][40];
    __shared__ u16 Bs[2][64][40];
    const int tid = threadIdx.x, lane = tid & 63, w = tid >> 6;
    const int wy = w >> 1, wx = w & 1, q = lane >> 4, l15 = lane & 15;
    const int row0 = blockIdx.y * TM, col0 = blockIdx.x * 64;
    uint4 ra[AL], rb[2];
    auto loadA = [&](int k0) {
#pragma unroll
        for (int j = 0; j < AL; j++) {
            int s = j * 256 + tid, p = s / (TM * 4), rr = (s >> 2) % TM, kg = s & 3;
            ra[j] = *(const uint4*)(Ap + (size_t)p * apl + (size_t)(row0 + rr) * lda + k0 + kg * 8);
        }
    };
    auto loadB = [&](int k0) {
#pragma unroll
        for (int j = 0; j < 2; j++) {
            int s = j * 256 + tid, p = s >> 8, rr = (s >> 2) & 63, kg = s & 3;
            rb[j] = *(const uint4*)(Bp + (size_t)p * bpl + (size_t)(col0 + rr) * ldb + k0 + kg * 8);
        }
    };
    v4f acc[MT][2] = {};
    loadA(0); loadB(0);
    for (int k0 = 0; k0 < K; k0 += 32) {
#pragma unroll
        for (int j = 0; j < AL; j++) {
            int s = j * 256 + tid, p = s / (TM * 4), rr = (s >> 2) % TM, kg = s & 3;
            *(uint4*)&As[p][rr][kg * 8] = ra[j];
        }
#pragma unroll
        for (int j = 0; j < 2; j++) {
            int s = j * 256 + tid, p = s >> 8, rr = (s >> 2) & 63, kg = s & 3;
            *(uint4*)&Bs[p][rr][kg * 8] = rb[j];
        }
        __syncthreads();
        if (k0 + 32 < K) { loadA(k0 + 32); loadB(k0 + 32); }
        v8s af[MT][2], bf[2][2];
#pragma unroll
        for (int mt = 0; mt < MT; mt++) {
            af[mt][0] = *(const v8s*)&As[0][wy * (TM / 2) + mt * 16 + l15][q * 8];
            af[mt][1] = *(const v8s*)&As[1][wy * (TM / 2) + mt * 16 + l15][q * 8];
        }
#pragma unroll
        for (int nt = 0; nt < 2; nt++) {
            bf[nt][0] = *(const v8s*)&Bs[0][wx * 32 + nt * 16 + l15][q * 8];
            bf[nt][1] = *(const v8s*)&Bs[1][wx * 32 + nt * 16 + l15][q * 8];
        }
#pragma unroll
        for (int mt = 0; mt < MT; mt++)
#pragma unroll
            for (int nt = 0; nt < 2; nt++) {
                v4f c = acc[mt][nt];
                c = MFMA(af[mt][0], bf[nt][0], c);
                c = MFMA(af[mt][0], bf[nt][1], c);
                c = MFMA(af[mt][1], bf[nt][0], c);
                acc[mt][nt] = c;
            }
        __syncthreads();
    }
#pragma unroll
    for (int mt = 0; mt < MT; mt++)
#pragma unroll
        for (int nt = 0; nt < 2; nt++)
            epi(row0 + wy * (TM / 2) + mt * 16 + q * 4, col0 + wx * 32 + nt * 16 + l15, acc[mt][nt]);
}

// ---------------- memupd: Se=wwT@eT^T, Sa=wwT@aT^T; mem=mem*(1-Se/B)+Sa/B; + row ssq partials ----------------
__global__ __launch_bounds__(256) void memupd2(const u16* __restrict__ wwT, const u16* __restrict__ eT,
                                               const u16* __restrict__ aT, float* __restrict__ memf,
                                               u16* __restrict__ mem_pl, u16* __restrict__ memT_pl,
                                               float* __restrict__ ssqp) {
    __shared__ u16 As[2][64][40], Be[2][64][40], Ba[2][64][40];
    __shared__ float ssqs[64];
    const int tid = threadIdx.x, lane = tid & 63, w = tid >> 6;
    const int wy = w >> 1, wx = w & 1, q = lane >> 4, l15 = lane & 15;
    const int row0 = blockIdx.y * 64, col0 = blockIdx.x * 64;  // row=n, col=m
    if (tid < 64) ssqs[tid] = 0.f;
    uint4 rA[2], rE[2], rB[2];
    auto loadAll = [&](int k0) {
#pragma unroll
        for (int j = 0; j < 2; j++) {
            int s = j * 256 + tid, p = s >> 8, rr = (s >> 2) & 63, kg = s & 3;
            rA[j] = *(const uint4*)(wwT + (size_t)p * PL_W + (size_t)(row0 + rr) * B_ + k0 + kg * 8);
            rE[j] = *(const uint4*)(eT + (size_t)p * PL_H + (size_t)(col0 + rr) * B_ + k0 + kg * 8);
            rB[j] = *(const uint4*)(aT + (size_t)p * PL_H + (size_t)(col0 + rr) * B_ + k0 + kg * 8);
        }
    };
    v4f ae[2][2] = {}, aa[2][2] = {};
    loadAll(0);
    for (int k0 = 0; k0 < B_; k0 += 32) {
#pragma unroll
        for (int j = 0; j < 2; j++) {
            int s = j * 256 + tid, p = s >> 8, rr = (s >> 2) & 63, kg = s & 3;
            *(uint4*)&As[p][rr][kg * 8] = rA[j];
            *(uint4*)&Be[p][rr][kg * 8] = rE[j];
            *(uint4*)&Ba[p][rr][kg * 8] = rB[j];
        }
        __syncthreads();
        if (k0 + 32 < B_) loadAll(k0 + 32);
        v8s af[2][2], be[2][2], ba[2][2];
#pragma unroll
        for (int mt = 0; mt < 2; mt++) {
            af[mt][0] = *(const v8s*)&As[0][wy * 32 + mt * 16 + l15][q * 8];
            af[mt][1] = *(const v8s*)&As[1][wy * 32 + mt * 16 + l15][q * 8];
            be[mt][0] = *(const v8s*)&Be[0][wx * 32 + mt * 16 + l15][q * 8];
            be[mt][1] = *(const v8s*)&Be[1][wx * 32 + mt * 16 + l15][q * 8];
            ba[mt][0] = *(const v8s*)&Ba[0][wx * 32 + mt * 16 + l15][q * 8];
            ba[mt][1] = *(const v8s*)&Ba[1][wx * 32 + mt * 16 + l15][q * 8];
        }
#pragma unroll
        for (int mt = 0; mt < 2; mt++)
#pragma unroll
            for (int nt = 0; nt < 2; nt++) {
                v4f c = ae[mt][nt];
                c = MFMA(af[mt][0], be[nt][0], c);
                c = MFMA(af[mt][0], be[nt][1], c);
                c = MFMA(af[mt][1], be[nt][0], c);
                ae[mt][nt] = c;
                v4f d = aa[mt][nt];
                d = MFMA(af[mt][0], ba[nt][0], d);
                d = MFMA(af[mt][0], ba[nt][1], d);
                d = MFMA(af[mt][1], ba[nt][0], d);
                aa[mt][nt] = d;
            }
        __syncthreads();
    }
    const float invB = 1.f / (float)B_;
#pragma unroll
    for (int mt = 0; mt < 2; mt++)
#pragma unroll
        for (int nt = 0; nt < 2; nt++) {
            int r0 = row0 + wy * 32 + mt * 16 + q * 4;
            int c  = col0 + wx * 32 + nt * 16 + l15;
            u16 hv[4][2];
#pragma unroll
            for (int r = 0; r < 4; r++) {
                size_t idx = (size_t)(r0 + r) * M_ + c;
                float old = memf[idx];
                float nv = old * (1.f - ae[mt][nt][r] * invB) + aa[mt][nt][r] * invB;
                memf[idx] = nv;
                u16 h, m; split2(nv, h, m);
                mem_pl[idx] = h; mem_pl[PL_MEM + idx] = m;
                hv[r][0] = h; hv[r][1] = m;
                atomicAdd(&ssqs[r0 + r - row0], nv * nv);
            }
            size_t tb = (size_t)c * N_ + r0;
            *(ushort4*)&memT_pl[tb] = make_ushort4(hv[0][0], hv[1][0], hv[2][0], hv[3][0]);
            *(ushort4*)&memT_pl[PL_MEM + tb] = make_ushort4(hv[0][1], hv[1][1], hv[2][1], hv[3][1]);
        }
    __syncthreads();
    if (tid < 64) ssqp[(size_t)(row0 + tid) * 8 + blockIdx.x] = ssqs[tid];
}

// ---------------- logits: raw = kh @ mem^T scaled by invn (from ssq partials) ----------------
__global__ __launch_bounds__(256) void logits2(const u16* __restrict__ khp, const u16* __restrict__ memp,
                                               const float* __restrict__ ssqp, float* __restrict__ logits) {
    __shared__ u16 As[2][64][40], Bs[2][64][40];
    __shared__ float invn_s[64];
    const int tid = threadIdx.x, lane = tid & 63, w = tid >> 6;
    const int wy = w >> 1, wx = w & 1, q = lane >> 4, l15 = lane & 15;
    const int row0 = blockIdx.y * 64, col0 = blockIdx.x * 64;  // row in [0,512), col=n
    if (tid < 64) {
        float s = 0.f;
#pragma unroll
        for (int j = 0; j < 8; j++) s += ssqp[(size_t)(col0 + tid) * 8 + j];
        invn_s[tid] = 1.f / (sqrtf(s) + EPS_);
    }
    uint4 ra[2], rb[2];
    auto loadAll = [&](int k0) {
#pragma unroll
        for (int j = 0; j < 2; j++) {
            int s = j * 256 + tid, p = s >> 8, rr = (s >> 2) & 63, kg = s & 3;
            ra[j] = *(const uint4*)(khp + (size_t)p * PL_KH + (size_t)(row0 + rr) * M_ + k0 + kg * 8);
            rb[j] = *(const uint4*)(memp + (size_t)p * PL_MEM + (size_t)(col0 + rr) * M_ + k0 + kg * 8);
        }
    };
    v4f acc[2][2] = {};
    loadAll(0);
    for (int k0 = 0; k0 < M_; k0 += 32) {
#pragma unroll
        for (int j = 0; j < 2; j++) {
            int s = j * 256 + tid, p = s >> 8, rr = (s >> 2) & 63, kg = s & 3;
            *(uint4*)&As[p][rr][kg * 8] = ra[j];
            *(uint4*)&Bs[p][rr][kg * 8] = rb[j];
        }
        __syncthreads();
        if (k0 + 32 < M_) loadAll(k0 + 32);
        v8s af[2][2], bf[2][2];
#pragma unroll
        for (int mt = 0; mt < 2; mt++) {
            af[mt][0] = *(const v8s*)&As[0][wy * 32 + mt * 16 + l15][q * 8];
            af[mt][1] = *(const v8s*)&As[1][wy * 32 + mt * 16 + l15][q * 8];
            bf[mt][0] = *(const v8s*)&Bs[0][wx * 32 + mt * 16 + l15][q * 8];
            bf[mt][1] = *(const v8s*)&Bs[1][wx * 32 + mt * 16 + l15][q * 8];
        }
#pragma unroll
        for (int mt = 0; mt < 2; mt++)
#pragma unroll
            for (int nt = 0; nt < 2; nt++) {
                v4f c = acc[mt][nt];
                c = MFMA(af[mt][0], bf[nt][0], c);
                c = MFMA(af[mt][0], bf[nt][1], c);
                c = MFMA(af[mt][1], bf[nt][0], c);
                acc[mt][nt] = c;
            }
        __syncthreads();
    }
#pragma unroll
    for (int mt = 0; mt < 2; mt++)
#pragma unroll
        for (int nt = 0; nt < 2; nt++) {
            int r0 = row0 + wy * 32 + mt * 16 + q * 4;
            int c  = col0 + wx * 32 + nt * 16 + l15;
            float in_ = invn_s[c - col0];
#pragma unroll
            for (int r = 0; r < 4; r++)
                logits[(size_t)(r0 + r) * N_ + c] = acc[mt][nt][r] * in_;
        }
}

// ---------------- xwx GEMM: rows (t*256+b), A split from f32 on the fly, out -> d_out[b][t][:] ----------------
__global__ __launch_bounds__(256) void gemm2_xwx(const float* __restrict__ x, const u16* __restrict__ WxT,
                                                 float* __restrict__ outbuf) {
    __shared__ u16 As[2][64][40];
    __shared__ u16 Bs[2][64][40];
    const int tid = threadIdx.x, lane = tid & 63, w = tid >> 6;
    const int wy = w >> 1, wx = w & 1, q = lane >> 4, l15 = lane & 15;
    const int row0 = blockIdx.y * 64, col0 = blockIdx.x * 64;
    const int sr = tid >> 2, ss = (tid & 3) * 8;
    const int arow = row0 + sr, ab = arow & 255, at = arow >> 8;
    const float* Asrc = x + ((size_t)ab * T_ + at) * I_ + ss;
    v4f acc[2][2] = {};
    for (int k0 = 0; k0 < I_; k0 += 32) {
        float4 f0 = *(const float4*)(Asrc + k0);
        float4 f1 = *(const float4*)(Asrc + k0 + 4);
        float av8[8] = {f0.x, f0.y, f0.z, f0.w, f1.x, f1.y, f1.z, f1.w};
#pragma unroll
        for (int j = 0; j < 8; j++) {
            u16 h, m; split2(av8[j], h, m);
            As[0][sr][ss + j] = h; As[1][sr][ss + j] = m;
        }
#pragma unroll
        for (int p = 0; p < 2; p++)
            *(uint4*)&Bs[p][sr][ss] = *(const uint4*)&WxT[(size_t)p * PL_WXT + (size_t)(col0 + sr) * I_ + k0 + ss];
        __syncthreads();
        v8s af[2][2], bf[2][2];
#pragma unroll
        for (int mt = 0; mt < 2; mt++) {
            af[mt][0] = *(const v8s*)&As[0][wy * 32 + mt * 16 + l15][q * 8];
            af[mt][1] = *(const v8s*)&As[1][wy * 32 + mt * 16 + l15][q * 8];
            bf[mt][0] = *(const v8s*)&Bs[0][wx * 32 + mt * 16 + l15][q * 8];
            bf[mt][1] = *(const v8s*)&Bs[1][wx * 32 + mt * 16 + l15][q * 8];
        }
#pragma unroll
        for (int mt = 0; mt < 2; mt++)
#pragma unroll
            for (int nt = 0; nt < 2; nt++) {
                v4f c = acc[mt][nt];
                c = MFMA(af[mt][0], bf[nt][0], c);
                c = MFMA(af[mt][0], bf[nt][1], c);
                c = MFMA(af[mt][1], bf[nt][0], c);
                acc[mt][nt] = c;
            }
        __syncthreads();
    }
#pragma unroll
    for (int mt = 0; mt < 2; mt++)
#pragma unroll
        for (int nt = 0; nt < 2; nt++) {
            int r0 = row0 + wy * 32 + mt * 16 + q * 4;
            int c  = col0 + wx * 32 + nt * 16 + l15;
#pragma unroll
            for (int r = 0; r < 4; r++) {
                int row = r0 + r, b = row & 255, t = row >> 8;
                outbuf[((size_t)b * T_ + t) * O_ + c] = acc[mt][nt][r];
            }
        }
}

// ---------------- decomp: transpose + split2: in f32 [R][ldin] cols c0.. -> planes [C][R] ----------------
__global__ __launch_bounds__(256) void decomp_t(const float* __restrict__ in, int ldin, int c0,
                                                int R, u16* __restrict__ outp, int opl) {
    __shared__ float Ls[32][33];
    const int r0 = blockIdx.x * 32, cB = blockIdx.y * 32;
    const int tid = threadIdx.x;
    int lr = tid >> 3, lc = (tid & 7) * 4;
#pragma unroll
    for (int j = 0; j < 4; j++)
        Ls[lr][lc + j] = in[(size_t)(r0 + lr) * ldin + c0 + cB + lc + j];
    __syncthreads();
    int lc2 = tid >> 3, lr2 = (tid & 7) * 4;
    u16 hv[4], mv[4];
#pragma unroll
    for (int j = 0; j < 4; j++) split2(Ls[lr2 + j][lc2], hv[j], mv[j]);
    size_t base = (size_t)(cB + lc2) * R + r0 + lr2;
    *(ushort4*)&outp[0 * (size_t)opl + base] = make_ushort4(hv[0], hv[1], hv[2], hv[3]);
    *(ushort4*)&outp[1 * (size_t)opl + base] = make_ushort4(mv[0], mv[1], mv[2], mv[3]);
}

// ---------------- init / misc ----------------
__global__ __launch_bounds__(512) void wh6_kernel(const float* __restrict__ Whw, const float* __restrict__ Whr,
                                                  float* __restrict__ w6w, float* __restrict__ w6r) {
    int k = threadIdx.x;
    const float* src = blockIdx.x ? Whr : Whw;
    float* dst = blockIdx.x ? w6r : w6w;
#pragma unroll
    for (int j = 0; j < 6; j++) dst[k * 6 + j] = src[(size_t)k * (M_ + 6) + M_ + j];
}
__global__ __launch_bounds__(256) void init_mem(const float* __restrict__ mem0, float* __restrict__ memf,
                                                u16* __restrict__ mem_pl, u16* __restrict__ memT_pl) {
    int n = blockIdx.x;
    for (int c = threadIdx.x; c < M_; c += 256) {
        float v = mem0[(size_t)n * M_ + c];
        size_t idx = (size_t)n * M_ + c;
        memf[idx] = v;
        u16 h, m; split2(v, h, m);
        mem_pl[idx] = h; mem_pl[PL_MEM + idx] = m;
        size_t tb = (size_t)c * N_ + n;
        memT_pl[tb] = h; memT_pl[PL_MEM + tb] = m;
    }
}
__global__ __launch_bounds__(256) void init_w(const float* __restrict__ wr0, const float* __restrict__ ww0,
                                              float* __restrict__ wrf, float* __restrict__ wwf,
                                              u16* __restrict__ wr_pl, u16* __restrict__ wwT_pl) {
    int b = blockIdx.x;
    for (int n = threadIdx.x; n < N_; n += 256) {
        size_t idx = (size_t)b * N_ + n;
        float vw = ww0[idx]; wwf[idx] = vw;
        u16 h, m; split2(vw, h, m);
        size_t tb = (size_t)n * B_ + b;
        wwT_pl[tb] = h; wwT_pl[PL_W + tb] = m;
        float vr = wr0[idx]; wrf[idx] = vr;
        split2(vr, h, m);
        wr_pl[idx] = h; wr_pl[PL_W + idx] = m;
    }
}
__global__ __launch_bounds__(64) void init_h(const float* __restrict__ h0, float* __restrict__ hf,
                                             u16* __restrict__ hp) {
    int b = blockIdx.x;
    for (int c = threadIdx.x; c < H_; c += 64) {
        size_t idx = (size_t)b * H_ + c;
        float v = h0[idx];
        hf[idx] = v;
        u16 h, m; split2(v, h, m);
        hp[idx] = h; hp[PL_H + idx] = m;
    }
}

// ---------------- addressing tail (incl. per-row scalars, ||k||, softmax, shift, sharpen) ----------------
__global__ __launch_bounds__(256) void addr_k2(const float* __restrict__ logits, const float* __restrict__ hf,
                                               const float* __restrict__ w6w, const float* __restrict__ w6r,
                                               const float* __restrict__ bhw, const float* __restrict__ bhr,
                                               const u16* __restrict__ khp,
                                               float* __restrict__ wwf, float* __restrict__ wrf,
                                               u16* __restrict__ wwT_pl, u16* __restrict__ wr_pl) {
    __shared__ float wgs[N_];
    __shared__ float red[8];
    int row = blockIdx.x, head = row >> 8, b = row & 255;
    const float* w6 = head ? w6r : w6w;
    const float* bias = head ? bhr : bhw;
    float* wf = head ? wrf : wwf;
    int tid = threadIdx.x;
    // per-row scalars: d[6] = h . w6, ssq = ||k||^2
    float d0 = 0, d1 = 0, d2 = 0, d3 = 0, d4 = 0, d5 = 0, ssq = 0;
#pragma unroll
    for (int j = 0; j < 2; j++) {
        int k = tid + j * 256;
        float hv = hf[(size_t)b * H_ + k];
        const float* wk = w6 + k * 6;
        d0 += hv * wk[0]; d1 += hv * wk[1]; d2 += hv * wk[2];
        d3 += hv * wk[3]; d4 += hv * wk[4]; d5 += hv * wk[5];
        size_t ki = (size_t)row * M_ + k;
        float kv = bf2f(khp[ki]) + bf2f(khp[PL_KH + ki]);
        ssq += kv * kv;
    }
    d0 = block_sum_(d0, red); d1 = block_sum_(d1, red); d2 = block_sum_(d2, red);
    d3 = block_sum_(d3, red); d4 = block_sum_(d4, red); d5 = block_sum_(d5, red);
    ssq = block_sum_(ssq, red);
    float beta = softplus_(d0 + bias[M_]);
    float g = sigm_(d1 + bias[M_ + 1]);
    float a0 = d2 + bias[M_ + 2], a1 = d3 + bias[M_ + 3], a2 = d4 + bias[M_ + 4];
    float mx3 = fmaxf(a0, fmaxf(a1, a2));
    float e0 = expf(a0 - mx3), e1 = expf(a1 - mx3), e2 = expf(a2 - mx3);
    float es = e0 + e1 + e2;
    float s0 = e0 / es, s1 = e1 / es, s2 = e2 / es;
    float gamma = 1.f + softplus_(d5 + bias[M_ + 5]);
    float rowsc = beta / (sqrtf(ssq) + EPS_);
    // softmax over logits*rowsc
    float l[4];
#pragma unroll
    for (int j = 0; j < 4; j++) l[j] = logits[(size_t)row * N_ + tid * 4 + j] * rowsc;
    float mx = fmaxf(fmaxf(l[0], l[1]), fmaxf(l[2], l[3]));
    mx = block_max_(mx, red);
    float ex[4], sum = 0.f;
#pragma unroll
    for (int j = 0; j < 4; j++) { ex[j] = expf(l[j] - mx); sum += ex[j]; }
    sum = block_sum_(sum, red);
    float inv = 1.f / sum;
    float wprev[4];
#pragma unroll
    for (int j = 0; j < 4; j++) wprev[j] = wf[(size_t)b * N_ + tid * 4 + j];
#pragma unroll
    for (int j = 0; j < 4; j++) wgs[tid * 4 + j] = g * ex[j] * inv + (1.f - g) * wprev[j];
    __syncthreads();
    float wp[4], psum = 0.f;
#pragma unroll
    for (int j = 0; j < 4; j++) {
        int n = tid * 4 + j;
        float wt = s0 * wgs[(n + 1) & (N_ - 1)] + s1 * wgs[n] + s2 * wgs[(n - 1) & (N_ - 1)];
        float v = expf(gamma * logf(wt));
        wp[j] = v; psum += v;
    }
    psum = block_sum_(psum, red);
    float invp = 1.f / (psum + EPS_);
#pragma unroll
    for (int j = 0; j < 4; j++) {
        int n = tid * 4 + j;
        float val = wp[j] * invp;
        wf[(size_t)b * N_ + n] = val;
        u16 h, m; split2(val, h, m);
        if (head == 0) {
            size_t tb = (size_t)n * B_ + b;
            wwT_pl[tb] = h; wwT_pl[PL_W + tb] = m;
        } else {
            size_t idx = (size_t)b * N_ + n;
            wr_pl[idx] = h; wr_pl[PL_W + idx] = m;
        }
    }
}

// ---------------- host ----------------
extern "C" void kernel_launch(void* const* d_in, const int* in_sizes, int n_in,
                              void* d_out, int out_size, void* d_ws, size_t ws_size,
                              hipStream_t stream) {
    (void)in_sizes; (void)n_in; (void)out_size; (void)ws_size;
    const float* x    = (const float*)d_in[0];
    const float* mem0 = (const float*)d_in[1];
    const float* wr0  = (const float*)d_in[2];
    const float* ww0  = (const float*)d_in[3];
    const float* h0   = (const float*)d_in[4];
    const float* Wx   = (const float*)d_in[5];
    const float* Wr   = (const float*)d_in[6];
    const float* bh   = (const float*)d_in[7];
    const float* Whr  = (const float*)d_in[8];
    const float* bhr  = (const float*)d_in[9];
    const float* Whw  = (const float*)d_in[10];
    const float* bhw  = (const float*)d_in[11];
    const float* Wea  = (const float*)d_in[12];
    const float* bea  = (const float*)d_in[13];
    const float* Wo   = (const float*)d_in[14];
    const float* bo   = (const float*)d_in[15];
    float* out = (float*)d_out;

    char* wsb = (char*)d_ws;
    size_t off = 0;
    auto carveU = [&](size_t elems) { u16* p = (u16*)(wsb + off); off += elems * sizeof(u16); return p; };
    u16* BigT    = carveU(2 * (size_t)PL_BIG);
    u16* WxT     = carveU(2 * (size_t)PL_WXT);
    u16* WrT     = carveU(2 * (size_t)PL_WRT);
    u16* mem_pl  = carveU(2 * (size_t)PL_MEM);
    u16* memT_pl = carveU(2 * (size_t)PL_MEM);
    u16* wwT_pl  = carveU(2 * (size_t)PL_W);
    u16* wr_pl   = carveU(2 * (size_t)PL_W);
    u16* h_pl    = carveU(2 * (size_t)PL_H);
    u16* r_pl    = carveU(2 * (size_t)PL_H);
    u16* eT_pl   = carveU(2 * (size_t)PL_H);
    u16* aT_pl   = carveU(2 * (size_t)PL_H);
    u16* kh_pl   = carveU(2 * (size_t)PL_KH);
    auto carveF = [&](size_t elems) { float* p = (float*)(wsb + off); off += elems * sizeof(float); return p; };
    float* memf   = carveF((size_t)N_ * M_);
    float* wwf    = carveF((size_t)B_ * N_);
    float* wrf    = carveF((size_t)B_ * N_);
    float* hf     = carveF((size_t)B_ * H_);
    float* logits = carveF((size_t)2 * B_ * N_);
    float* ssqp   = carveF((size_t)N_ * 8);
    float* w6w    = carveF(H_ * 6);
    float* w6r    = carveF(H_ * 6);

    // ---- prologue: weight decomposition + state init ----
    decomp_t<<<dim3(16, 16), 256, 0, stream>>>(Whw, M_ + 6, 0, 512, BigT, PL_BIG);                       // rows 0-511
    decomp_t<<<dim3(16, 16), 256, 0, stream>>>(Whr, M_ + 6, 0, 512, BigT + (size_t)512 * 512, PL_BIG);   // rows 512-1023
    decomp_t<<<dim3(16, 16), 256, 0, stream>>>(Wo, 512, 0, 512, BigT + (size_t)1024 * 512, PL_BIG);      // rows 1024-1535
    decomp_t<<<dim3(16, 32), 256, 0, stream>>>(Wea, 1024, 0, 512, BigT + (size_t)1536 * 512, PL_BIG);    // rows 1536-2559
    decomp_t<<<dim3(16, 16), 256, 0, stream>>>(Wx, 512, 0, 512, WxT, PL_WXT);
    decomp_t<<<dim3(16, 16), 256, 0, stream>>>(Wr, 512, 0, 512, WrT, PL_WRT);
    wh6_kernel<<<2, 512, 0, stream>>>(Whw, Whr, w6w, w6r);
    init_mem<<<N_, 256, 0, stream>>>(mem0, memf, mem_pl, memT_pl);
    init_w<<<B_, 256, 0, stream>>>(wr0, ww0, wrf, wwf, wr_pl, wwT_pl);
    init_h<<<B_, 64, 0, stream>>>(h0, hf, h_pl);
    // xwx for all (t,b) -> stored in d_out slots [b][t][:]
    gemm2_xwx<<<dim3(8, 512), 256, 0, stream>>>(x, WxT, out);
    // ea for step 0 from h0
    gemm2<32, EpiEA0><<<dim3(16, 8), 256, 0, stream>>>(
        h_pl, 512, PL_H, BigT + (size_t)1536 * 512, 512, PL_BIG, 512, EpiEA0{bea, eT_pl, aT_pl});

    for (int t = 0; t < T_; t++) {
        // 1. mem update + row-ssq partials  [n x m, K=256]
        memupd2<<<dim3(8, 16), 256, 0, stream>>>(wwT_pl, eT_pl, aT_pl, memf, mem_pl, memT_pl, ssqp);
        // 2. r = wr @ mem  [256 x 512, K=1024]
        gemm2<32, EpiR><<<dim3(8, 8), 256, 0, stream>>>(
            wr_pl, 1024, PL_W, memT_pl, 1024, PL_MEM, 1024, EpiR{r_pl});
        // 3. h = tanh(xwx + r @ Wr + bh)  [256 x 512, K=512]
        gemm2<32, EpiH><<<dim3(8, 8), 256, 0, stream>>>(
            r_pl, 512, PL_H, WrT, 512, PL_WRT, 512, EpiH{out + (size_t)t * O_, bh, hf, h_pl});
        // 4. fused: h @ [Whw_k | Whr_k | Wo | Wea] -> keys, out_t, ea_{t+1}  [256 x 2560, K=512]
        gemm2<32, EpiFused><<<dim3(40, 8), 256, 0, stream>>>(
            h_pl, 512, PL_H, BigT, 512, PL_BIG, 512,
            EpiFused{bhw, bhr, bo, bea, kh_pl, out + (size_t)t * O_, eT_pl, aT_pl});
        // 5. logits = (kh @ mem^T) * invn  [512 x 1024, K=512]
        logits2<<<dim3(16, 8), 256, 0, stream>>>(kh_pl, mem_pl, ssqp, logits);
        // 6. addressing tail -> ww/wr masters + planes
        addr_k2<<<2 * B_, 256, 0, stream>>>(logits, hf, w6w, w6r, bhw, bhr, kh_pl,
                                            wwf, wrf, wwT_pl, wr_pl);
    }
}